// Round 13
// baseline (290.640 us; speedup 1.0000x reference)
//
#include <hip/hip_runtime.h>
#include <hip/hip_bf16.h>

#define B 16
#define L 64
#define P 1024
#define V 64
#define Q 16
#define LN64 4.158883083359672f

#define CHBC 16           // p per k_bc block
#define NCH_BC (P / CHBC) // 64

typedef unsigned short ushort8_t __attribute__((ext_vector_type(8)));

typedef const __attribute__((address_space(1))) void* gld_gptr_t;
typedef __attribute__((address_space(3))) void* gld_lptr_t;

static __device__ __forceinline__ float bf2f(ushort u) {
    return __uint_as_float(((unsigned int)u) << 16);
}
static __device__ __forceinline__ ushort f2bf(float f) {
    unsigned int x = __float_as_uint(f);
    unsigned int r = (x + 0x7fffu + ((x >> 16) & 1u)) >> 16;
    return (ushort)r;
}
// packed bf16-pair helpers: word = bf16(lo) | bf16(hi)<<16
static __device__ __forceinline__ float pklo(unsigned int w) {
    return __uint_as_float(w << 16);
}
static __device__ __forceinline__ float pkhi(unsigned int w) {
    return __uint_as_float(w & 0xffff0000u);
}

static __device__ __forceinline__ float wsum64(float v) {
#pragma unroll
    for (int m = 32; m > 0; m >>= 1) v += __shfl_xor(v, m, 64);
    return v;
}
static __device__ __forceinline__ float wmax64(float v) {
#pragma unroll
    for (int m = 32; m > 0; m >>= 1) v = fmaxf(v, __shfl_xor(v, m, 64));
    return v;
}

// ---------------------------------------------------------------------------
// K_uhat v12: k_bc's proven barrier-free streaming structure applied to the
// producer. Block = (p, l-half), 256 thr. Wave w owns v in [16w,16w+16) x ALL
// 16 b -> each wave reads only ITS OWN staged 1 KB per l:
//  - wave-private 6-slot LDS ring (24 KB block total), NO s_barrier in loop,
//    per-wave counted vmcnt(4) (depth-5 prefetch ~850 cyc coverage);
//  - outputs for all 32 l packed in 64 VGPR (uint2 uout[32], full unroll ->
//    static indices), ONE terminal store burst: no wait ever crosses a store
//    (v2..v11 all coupled stage-waits to store retirement via the shared
//    in-order vmcnt + 4-wave barrier lockstep -- the persistent ~137us).
//  - coalescing kept: per-lane source chunk (l&~3)|((l&3)^((l>>3)&3)) ->
//    contiguous 1 KB per stage inst; read XOR q4^((vl>>1)&3) -> 2-way banks.
// lane = (bq = lane>>4 -> b = bq*4+i, vl = lane&15 -> v = w*16+vl).
// uhat layout [b][l][p][v]. Numerics identical to v9-v11.
// ---------------------------------------------------------------------------
__global__ __launch_bounds__(256) void k_uhat(const float* __restrict__ Wt,
                                              const float* __restrict__ x,
                                              ushort* __restrict__ uhat) {
    const int t = threadIdx.x;
    const int w = t >> 6;          // v-quarter
    const int lane = t & 63;
    const int bq = lane >> 4;      // b-quad: b = bq*4 + i
    const int vl = lane & 15;      // v-local: v = w*16 + vl
    const int p = blockIdx.x >> 1;
    const int l0 = (blockIdx.x & 1) * 32;

    __shared__ float xs[B * Q];            // 1 KB
    __shared__ char wls[4][6][1024];       // 24 KB: per-wave 6-slot ring

    {
        const int b = t >> 4, q = t & 15;
        xs[t] = x[((size_t)b * P + p) * Q + q];
    }
    __syncthreads();

    // pack this lane's 4 b-rows of x as bf16 pairs (32 VGPR)
    unsigned int xp[4][8];
#pragma unroll
    for (int i = 0; i < 4; ++i) {
        const int b = bq * 4 + i;
#pragma unroll
        for (int j = 0; j < 8; ++j) {
            unsigned int lo = f2bf(xs[b * Q + 2 * j]);
            unsigned int hi = f2bf(xs[b * Q + 2 * j + 1]);
            xp[i][j] = lo | (hi << 16);
        }
    }

    // stage source: swizzled 16B chunk within this wave's 1KB quarter
    const int c = (lane & ~3) | ((lane & 3) ^ ((lane >> 3) & 3));
    const char* gW = (const char*)Wt + ((size_t)l0 * P + p) * (V * Q * 4)
                     + w * 1024 + c * 16;
    const size_t LSTRIDE = (size_t)P * V * Q * 4;   // 4 MB per l
    char* wbase = &wls[w][0][0];
    const int xsw = (vl >> 1) & 3;                  // read-side XOR

    uint2 uout[32];                                 // 64 VGPR output buffer

#define STAGE(li)                                                             \
    __builtin_amdgcn_global_load_lds(                                         \
        (gld_gptr_t)(gW + (size_t)(li) * LSTRIDE),                            \
        (gld_lptr_t)(wbase + ((li) % 6) * 1024), 16, 0, 0);

#define COMPUTE(li)                                                           \
    {                                                                         \
        const char* sb = wbase + ((li) % 6) * 1024 + vl * 64;                 \
        float4 Wr[4];                                                         \
        Wr[0] = *(const float4*)(sb + ((0 ^ xsw) << 4));                      \
        Wr[1] = *(const float4*)(sb + ((1 ^ xsw) << 4));                      \
        Wr[2] = *(const float4*)(sb + ((2 ^ xsw) << 4));                      \
        Wr[3] = *(const float4*)(sb + ((3 ^ xsw) << 4));                      \
        float uu[4];                                                          \
        _Pragma("unroll")                                                     \
        for (int i = 0; i < 4; ++i) {                                         \
            float u = 0.f;                                                    \
            _Pragma("unroll")                                                 \
            for (int j = 0; j < 8; ++j) {                                     \
                const float4 Wq = Wr[j >> 1];                                 \
                const float wlo = (j & 1) ? Wq.z : Wq.x;                      \
                const float whi = (j & 1) ? Wq.w : Wq.y;                      \
                u = fmaf(wlo, pklo(xp[i][j]), u);                             \
                u = fmaf(whi, pkhi(xp[i][j]), u);                             \
            }                                                                 \
            uu[i] = u;                                                        \
        }                                                                     \
        uout[li].x = (unsigned)f2bf(uu[0]) | ((unsigned)f2bf(uu[1]) << 16);   \
        uout[li].y = (unsigned)f2bf(uu[2]) | ((unsigned)f2bf(uu[3]) << 16);   \
    }

#define WAITV(N)                                                              \
    asm volatile("s_waitcnt vmcnt(" #N ")" ::: "memory");                     \
    __builtin_amdgcn_sched_barrier(0);

    STAGE(0);
    STAGE(1);
    STAGE(2);
    STAGE(3);
    STAGE(4);

    // self-paced stream: queue holds ONLY stages; wait(4) retires S(li)
#pragma unroll
    for (int li = 0; li < 27; ++li) {
        WAITV(4);
        STAGE(li + 5);
        COMPUTE(li);
    }
    WAITV(4); COMPUTE(27);
    WAITV(3); COMPUTE(28);
    WAITV(2); COMPUTE(29);
    WAITV(1); COMPUTE(30);
    WAITV(0); COMPUTE(31);

    // terminal store burst (never waited on inside the kernel)
    const int v = w * 16 + vl;
#pragma unroll
    for (int li = 0; li < 32; ++li) {
#pragma unroll
        for (int i = 0; i < 4; ++i) {
            const int b = bq * 4 + i;
            const unsigned pairv = (i >> 1) ? uout[li].y : uout[li].x;
            const ushort us = (ushort)((i & 1) ? (pairv >> 16) : (pairv & 0xffffu));
            uhat[(((size_t)(b * L + l0 + li)) * P + p) * V + v] = us;
        }
    }

#undef STAGE
#undef COMPUTE
#undef WAITV
}

// ---------------------------------------------------------------------------
// K_s: per (b,l) block, iter-0 only (uniform c). s[v] = (1/64) sum_p u[p,v],
// fused squash. Thread t owns (pl = t>>4, v0 = (t&15)*4); ushort4 loads.
// ---------------------------------------------------------------------------
__global__ __launch_bounds__(256) void k_s(const ushort* __restrict__ uhat,
                                           float* __restrict__ vout) {
    const int l = blockIdx.x, b = blockIdx.y;
    const int t = threadIdx.x;
    const int w = t >> 6, lane = t & 63;
    const int pl = t >> 4;      // 0..15
    const int vg = t & 15;      // v0 = vg*4

    __shared__ float4 sl[4][16];

    const ushort* up = uhat + ((size_t)(b * L + l)) * P * V + (size_t)pl * V + vg * 4;

    float4 acc = {0.f, 0.f, 0.f, 0.f};
#pragma unroll 8
    for (int i = 0; i < 64; ++i) {
        ushort4 u = *reinterpret_cast<const ushort4*>(up + (size_t)i * 16 * V);
        acc.x += bf2f(u.x); acc.y += bf2f(u.y);
        acc.z += bf2f(u.z); acc.w += bf2f(u.w);
    }
    acc.x *= (1.f / 64.f); acc.y *= (1.f / 64.f);
    acc.z *= (1.f / 64.f); acc.w *= (1.f / 64.f);
#pragma unroll
    for (int m = 16; m <= 32; m <<= 1) {
        acc.x += __shfl_xor(acc.x, m, 64);
        acc.y += __shfl_xor(acc.y, m, 64);
        acc.z += __shfl_xor(acc.z, m, 64);
        acc.w += __shfl_xor(acc.w, m, 64);
    }
    if (lane < 16) sl[w][vg] = acc;
    __syncthreads();
    if (w == 0 && lane < 16) {
        float4 s0 = sl[0][vg], s1 = sl[1][vg], s2 = sl[2][vg], s3 = sl[3][vg];
        float4 s;
        s.x = s0.x + s1.x + s2.x + s3.x;
        s.y = s0.y + s1.y + s2.y + s3.y;
        s.z = s0.z + s1.z + s2.z + s3.z;
        s.w = s0.w + s1.w + s2.w + s3.w;
        float sq = s.x * s.x + s.y * s.y + s.z * s.z + s.w * s.w;
        sq += __shfl_xor(sq, 1, 64);
        sq += __shfl_xor(sq, 2, 64);
        sq += __shfl_xor(sq, 4, 64);
        sq += __shfl_xor(sq, 8, 64);
        float f = sqrtf(sq) / (1.0f + sq);
        float4 o = {s.x * f, s.y * f, s.z * f, s.w * f};
        *reinterpret_cast<float4*>(vout + (size_t)(b * L + l) * V + vg * 4) = o;
    }
}

// ---------------------------------------------------------------------------
// K_bc v6: block = (ch of 16 p, b), 512 threads (8 waves). u tile kept in
// REGISTERS (ur[8][2] ushort8/thread); LDS only vsh+bl (20 KB) -> 2 blocks/CU.
// phase 1: all 16 coalesced 1KB u-loads issued early, dot with v -> bl[p][l].
// phase 2: softmax over l per p (each wave 2 p's); b-logit update; optional T.
// phase 3: s-partial from registers, butterfly over pl8 -> sp[b][ch][l][v].
// ---------------------------------------------------------------------------
__global__ __launch_bounds__(512, 4) void k_bc(const ushort* __restrict__ uhat,
                                               const float* __restrict__ vv,
                                               float* __restrict__ bbuf,
                                               float* __restrict__ sp,
                                               float* __restrict__ Tsum,
                                               int add_prev, int do_T) {
    const int ch = blockIdx.x, b = blockIdx.y;
    const int p0 = ch * CHBC;
    const int t = threadIdx.x;
    const int w = t >> 6, lane = t & 63;
    const int pl8 = lane >> 3;   // p-local
    const int vg8 = lane & 7;    // v-octet
    const int l0 = w * 8;

    __shared__ float vsh[L][V];         // 16 KB
    __shared__ float bl[CHBC][L + 1];   // logits, then c in place
    __shared__ float twv[8];

    {
        const float4* vvp = reinterpret_cast<const float4*>(vv + (size_t)b * L * V);
        float4* vshp = reinterpret_cast<float4*>(&vsh[0][0]);
#pragma unroll
        for (int i = 0; i < 2; ++i) vshp[t + i * 512] = vvp[t + i * 512];
    }

    ushort8_t ur[8][2];
    {
        const ushort* ubase = uhat + (((size_t)(b * L + l0)) * P + p0 + pl8) * V + vg8 * 8;
#pragma unroll
        for (int li = 0; li < 8; ++li) {
#pragma unroll
            for (int ph = 0; ph < 2; ++ph)
                ur[li][ph] = *reinterpret_cast<const ushort8_t*>(
                    ubase + ((size_t)li * P + ph * 8) * V);
        }
    }
    __syncthreads();

#pragma unroll
    for (int li = 0; li < 8; ++li) {
        const int l = l0 + li;
        const float4 va = *reinterpret_cast<const float4*>(&vsh[l][vg8 * 8]);
        const float4 vb = *reinterpret_cast<const float4*>(&vsh[l][vg8 * 8 + 4]);
#pragma unroll
        for (int ph = 0; ph < 2; ++ph) {
            float d;
            d = bf2f(ur[li][ph][0]) * va.x;
            d = fmaf(bf2f(ur[li][ph][1]), va.y, d);
            d = fmaf(bf2f(ur[li][ph][2]), va.z, d);
            d = fmaf(bf2f(ur[li][ph][3]), va.w, d);
            d = fmaf(bf2f(ur[li][ph][4]), vb.x, d);
            d = fmaf(bf2f(ur[li][ph][5]), vb.y, d);
            d = fmaf(bf2f(ur[li][ph][6]), vb.z, d);
            d = fmaf(bf2f(ur[li][ph][7]), vb.w, d);
            d += __shfl_xor(d, 1, 64);
            d += __shfl_xor(d, 2, 64);
            d += __shfl_xor(d, 4, 64);
            if (vg8 == 0) bl[ph * 8 + pl8][l] = d;
        }
    }
    __syncthreads();

    float tloc = 0.f;
#pragma unroll
    for (int pi = 0; pi < 2; ++pi) {
        const int pli = w * 2 + pi;
        const int p = p0 + pli;
        float bv = bl[pli][lane];
        float* bp = bbuf + ((size_t)b * P + p) * L;
        if (add_prev) bv += bp[lane];
        bp[lane] = bv;
        float m = wmax64(bv);
        float e = __expf(bv - m);
        float ssum = wsum64(e);
        float cc = e / ssum;
        bl[pli][lane] = cc;
        if (do_T) tloc += cc * __logf(64.0f * (cc + 1e-12f));
    }
    if (do_T) {
        float dsum = wsum64(tloc);
        if (lane == 0) twv[w] = dsum;
    }
    __syncthreads();
    if (do_T && t == 0) {
        float s8 = twv[0] + twv[1] + twv[2] + twv[3] +
                   twv[4] + twv[5] + twv[6] + twv[7];
        atomicAdd(Tsum, s8 * (1.0f / LN64));
    }

    float* spb = sp + (size_t)(b * NCH_BC + ch) * L * V;
#pragma unroll
    for (int li = 0; li < 8; ++li) {
        const int l = l0 + li;
        const float cA = bl[pl8][l];
        const float cB = bl[8 + pl8][l];
        float4 pa, pb;
        pa.x = cA * bf2f(ur[li][0][0]) + cB * bf2f(ur[li][1][0]);
        pa.y = cA * bf2f(ur[li][0][1]) + cB * bf2f(ur[li][1][1]);
        pa.z = cA * bf2f(ur[li][0][2]) + cB * bf2f(ur[li][1][2]);
        pa.w = cA * bf2f(ur[li][0][3]) + cB * bf2f(ur[li][1][3]);
        pb.x = cA * bf2f(ur[li][0][4]) + cB * bf2f(ur[li][1][4]);
        pb.y = cA * bf2f(ur[li][0][5]) + cB * bf2f(ur[li][1][5]);
        pb.z = cA * bf2f(ur[li][0][6]) + cB * bf2f(ur[li][1][6]);
        pb.w = cA * bf2f(ur[li][0][7]) + cB * bf2f(ur[li][1][7]);
#pragma unroll
        for (int m = 8; m <= 32; m <<= 1) {
            pa.x += __shfl_xor(pa.x, m, 64);
            pa.y += __shfl_xor(pa.y, m, 64);
            pa.z += __shfl_xor(pa.z, m, 64);
            pa.w += __shfl_xor(pa.w, m, 64);
            pb.x += __shfl_xor(pb.x, m, 64);
            pb.y += __shfl_xor(pb.y, m, 64);
            pb.z += __shfl_xor(pb.z, m, 64);
            pb.w += __shfl_xor(pb.w, m, 64);
        }
        if (pl8 == 0) {
            *reinterpret_cast<float4*>(spb + (size_t)l * V + vg8 * 8) = pa;
            *reinterpret_cast<float4*>(spb + (size_t)l * V + vg8 * 8 + 4) = pb;
        }
    }
}

// ---------------------------------------------------------------------------
// K_v: chunk-reduce + squash. sp[b][ch][l][v]. grid (L/4, B); wave w -> l.
// ---------------------------------------------------------------------------
__global__ __launch_bounds__(256) void k_v(const float* __restrict__ sp,
                                           float* __restrict__ vout,
                                           float* __restrict__ norms) {
    const int b = blockIdx.y;
    const int w = threadIdx.x >> 6, lane = threadIdx.x & 63;
    const int l = blockIdx.x * 4 + w;
    const float* p = sp + ((size_t)b * NCH_BC * L + l) * V + lane;
    float s = 0.f;
#pragma unroll 8
    for (int ch = 0; ch < NCH_BC; ++ch) s += p[(size_t)ch * L * V];
    float sq = wsum64(s * s);
    float f = sqrtf(sq) / (1.0f + sq);
    vout[((size_t)b * L + l) * V + lane] = s * f;
    if (norms && lane == 0) norms[b * L + l] = sq / (1.0f + sq);
}

// ---------------------------------------------------------------------------
// K_final: T and D. One block, 64 threads (lane = l).
// ---------------------------------------------------------------------------
__global__ void k_final(const float* __restrict__ Tsum,
                        const float* __restrict__ norms,
                        float* __restrict__ out) {
    const int lane = threadIdx.x & 63;
    float n[B];
    float sum = 0.f;
#pragma unroll
    for (int b = 0; b < B; ++b) { n[b] = norms[b * L + lane]; sum += n[b]; }
    const float mean = sum * (1.0f / B);
    float var = 0.f;
#pragma unroll
    for (int b = 0; b < B; ++b) { float d = n[b] - mean; var = fmaf(d, d, var); }
    var *= (1.0f / B);
    float sd = sqrtf(var);
    float D = wmax64(sd);
    if (lane == 0) {
        out[B * L * V] = Tsum[0] * (1.0f / (B * P));
        out[B * L * V + 1] = D;
    }
}

extern "C" void kernel_launch(void* const* d_in, const int* in_sizes, int n_in,
                              void* d_out, int out_size, void* d_ws, size_t ws_size,
                              hipStream_t stream) {
    const float* x = (const float*)d_in[0];   // (B,P,Q)
    const float* W = (const float*)d_in[1];   // (L,P,V,Q)
    float* out = (float*)d_out;               // v (B,L,V) then T, D

    char* ws = (char*)d_ws;
    ushort* uhat = (ushort*)ws;                        // [b][l][p][v] bf16 = 128 MB
    size_t off = (size_t)B * L * P * V * 2;
    float* spbuf = (float*)(ws + off); off += (size_t)B * NCH_BC * L * V * 4;  // 16 MB
    float* vbuf  = (float*)(ws + off); off += (size_t)B * L * V * 4;
    float* bbuf  = (float*)(ws + off); off += (size_t)B * P * L * 4;           // 4 MB [b][p][l]
    float* norms = (float*)(ws + off); off += (size_t)B * L * 4;
    float* Tsum  = (float*)(ws + off); off += 256;

    hipMemsetAsync(Tsum, 0, sizeof(float), stream);

    // u_hat (barrier-free wave-private streaming, stores decoupled)
    hipLaunchKernelGGL(k_uhat, dim3(2048), dim3(256), 0, stream, W, x, uhat);
    // iter 0: uniform c -> v0
    hipLaunchKernelGGL(k_s, dim3(L, B), dim3(256), 0, stream, uhat, vbuf);
    // b1 = v0.u ; c1 ; partial s1 (fused, u in registers)
    hipLaunchKernelGGL(k_bc, dim3(NCH_BC, B), dim3(512), 0, stream,
                       uhat, vbuf, bbuf, spbuf, Tsum, 0, 0);
    // v1
    hipLaunchKernelGGL(k_v, dim3(L / 4, B), dim3(256), 0, stream,
                       spbuf, vbuf, (float*)nullptr);
    // b2 = b1 + v1.u ; c2 ; T partials ; partial s2
    hipLaunchKernelGGL(k_bc, dim3(NCH_BC, B), dim3(512), 0, stream,
                       uhat, vbuf, bbuf, spbuf, Tsum, 1, 1);
    // v2 -> out, norms
    hipLaunchKernelGGL(k_v, dim3(L / 4, B), dim3(256), 0, stream,
                       spbuf, out, norms);
    hipLaunchKernelGGL(k_final, dim3(1), dim3(64), 0, stream, Tsum, norms, out);
}

// Round 14
// 230.077 us; speedup vs baseline: 1.2632x; 1.2632x over previous
//
#include <hip/hip_runtime.h>
#include <hip/hip_bf16.h>

#define B 16
#define L 64
#define P 1024
#define V 64
#define Q 16
#define LN64 4.158883083359672f

#define CHBC 16           // p per k_bc block
#define NCH_BC (P / CHBC) // 64

typedef unsigned short ushort8_t __attribute__((ext_vector_type(8)));

typedef const __attribute__((address_space(1))) void* gld_gptr_t;
typedef __attribute__((address_space(3))) void* gld_lptr_t;

static __device__ __forceinline__ float bf2f(ushort u) {
    return __uint_as_float(((unsigned int)u) << 16);
}
static __device__ __forceinline__ ushort f2bf(float f) {
    unsigned int x = __float_as_uint(f);
    unsigned int r = (x + 0x7fffu + ((x >> 16) & 1u)) >> 16;
    return (ushort)r;
}

static __device__ __forceinline__ float wsum64(float v) {
#pragma unroll
    for (int m = 32; m > 0; m >>= 1) v += __shfl_xor(v, m, 64);
    return v;
}
static __device__ __forceinline__ float wmax64(float v) {
#pragma unroll
    for (int m = 32; m > 0; m >>= 1) v = fmaxf(v, __shfl_xor(v, m, 64));
    return v;
}

// ---------------------------------------------------------------------------
// K_uhat v13: WIDE STORES. Every prior variant stored bf16 scalars (2 B/lane,
// sub-dword) -- the one trait shared by all ~1.6-2.6 TB/s producers and by
// none of the 5-6 TB/s consumers. Thread remap: (lih = t>>7 selects l-parity,
// b = (t>>3)&15, vo = t&7). Per l each thread computes v = vo*8..vo*8+8 for
// ONE b and stores one uint4 (16 B/lane; 8x128 B contiguous per wave instr).
// W tile (4 KB/l) staged via coalesced global_load_lds (1 KB contiguous per
// instr, source chunk-swizzled (s&~3)|((s&3)^((s>>5)&3))); 6-slot ring,
// 2 l per step, 16 barrier steps; counted vmcnt never waits on stores
// (exact queue replay: 2,3,4..4,2). LDS reads: logical-q4 order ->
// addr v*64+((q4^(vo&3))<<4): 16-way b-broadcast, <=2-way banks (free).
// x[b] in 16 f32 regs. uhat layout [b][l][p][v] unchanged.
// ---------------------------------------------------------------------------
__global__ __launch_bounds__(256) void k_uhat(const float* __restrict__ Wt,
                                              const float* __restrict__ x,
                                              ushort* __restrict__ uhat) {
    const int t = threadIdx.x;
    const int w = t >> 6;          // wave / stage-quarter
    const int lane = t & 63;
    const int p = blockIdx.x >> 1;
    const int l0 = (blockIdx.x & 1) * 32;
    const int b   = (t >> 3) & 15; // this thread's batch row
    const int vo  = t & 7;         // v-octet: v = vo*8 .. vo*8+8
    const int lih = t >> 7;        // 0: waves 0,1 ; 1: waves 2,3
    const int vosw = vo & 3;

    __shared__ float xs[B * Q];        // 1 KB
    __shared__ char wls[6][4096];      // 24 KB: 6-slot tile ring

    {
        const int bb = t >> 4, q = t & 15;
        xs[t] = x[((size_t)bb * P + p) * Q + q];
    }
    __syncthreads();

    float xr[16];
    {
        const float4* xb = reinterpret_cast<const float4*>(&xs[b * Q]);
#pragma unroll
        for (int q4 = 0; q4 < 4; ++q4) {
            float4 v4 = xb[q4];
            xr[q4 * 4 + 0] = v4.x; xr[q4 * 4 + 1] = v4.y;
            xr[q4 * 4 + 2] = v4.z; xr[q4 * 4 + 3] = v4.w;
        }
    }

    // stage source: chunk-swizzled so LDS pos s holds logical (v=s>>2,
    // q4=(s&3)^((s>>5)&3)) -> read side gets bank-spread at logical order
    const int sc = w * 64 + lane;
    const int nsrc = (sc & ~3) | ((sc & 3) ^ ((sc >> 5) & 3));
    const char* gW = (const char*)Wt + ((size_t)l0 * P + p) * (V * Q * 4)
                     + (size_t)nsrc * 16;
    const size_t LSTRIDE = (size_t)P * V * Q * 4;   // 4 MB per l

    ushort* ub = uhat + ((size_t)(b * L + l0) * P + p) * V + vo * 8;

#define STAGE(li_)                                                            \
    __builtin_amdgcn_global_load_lds(                                         \
        (gld_gptr_t)(gW + (size_t)(li_) * LSTRIDE),                           \
        (gld_lptr_t)(&wls[(li_) % 6][w * 1024]), 16, 0, 0);

#define COMPUTE(s)                                                            \
    {                                                                         \
        const char* sb = &wls[(2 * (s)) % 6][0] + lih * 4096;                 \
        float d[8];                                                           \
        _Pragma("unroll")                                                     \
        for (int j = 0; j < 8; ++j) {                                         \
            const char* rb = sb + (vo * 8 + j) * 64;                          \
            const float4 W0 = *(const float4*)(rb + ((0 ^ vosw) << 4));       \
            const float4 W1 = *(const float4*)(rb + ((1 ^ vosw) << 4));       \
            const float4 W2 = *(const float4*)(rb + ((2 ^ vosw) << 4));       \
            const float4 W3 = *(const float4*)(rb + ((3 ^ vosw) << 4));       \
            float u = 0.f;                                                    \
            u = fmaf(W0.x, xr[0],  u); u = fmaf(W0.y, xr[1],  u);             \
            u = fmaf(W0.z, xr[2],  u); u = fmaf(W0.w, xr[3],  u);             \
            u = fmaf(W1.x, xr[4],  u); u = fmaf(W1.y, xr[5],  u);             \
            u = fmaf(W1.z, xr[6],  u); u = fmaf(W1.w, xr[7],  u);             \
            u = fmaf(W2.x, xr[8],  u); u = fmaf(W2.y, xr[9],  u);             \
            u = fmaf(W2.z, xr[10], u); u = fmaf(W2.w, xr[11], u);             \
            u = fmaf(W3.x, xr[12], u); u = fmaf(W3.y, xr[13], u);             \
            u = fmaf(W3.z, xr[14], u); u = fmaf(W3.w, xr[15], u);             \
            d[j] = u;                                                         \
        }                                                                     \
        uint4 pk;                                                             \
        pk.x = (unsigned)f2bf(d[0]) | ((unsigned)f2bf(d[1]) << 16);           \
        pk.y = (unsigned)f2bf(d[2]) | ((unsigned)f2bf(d[3]) << 16);           \
        pk.z = (unsigned)f2bf(d[4]) | ((unsigned)f2bf(d[5]) << 16);           \
        pk.w = (unsigned)f2bf(d[6]) | ((unsigned)f2bf(d[7]) << 16);           \
        *reinterpret_cast<uint4*>(ub + (size_t)(2 * (s) + lih) * P * V) = pk; \
    }

#define WAITB(N)                                                              \
    asm volatile("s_waitcnt vmcnt(" #N ")" ::: "memory");                     \
    __builtin_amdgcn_sched_barrier(0);                                        \
    __builtin_amdgcn_s_barrier();                                             \
    __builtin_amdgcn_sched_barrier(0);

    STAGE(0); STAGE(1); STAGE(2); STAGE(3);

    // step0: Q=[S0..S3] -> wait(2) retires S0,S1
    WAITB(2); STAGE(4); STAGE(5); COMPUTE(0);
    // step1: Q=[S2,S3,S4,S5,st0] -> wait(3) retires S2,S3
    WAITB(3); STAGE(6); STAGE(7); COMPUTE(1);
    // steady steps 2..13: Q=[S(2s),S(2s+1),st(s-2),S(2s+2),S(2s+3),st(s-1)]
    // -> wait(4) retires exactly S(2s),S(2s+1); stores never waited on.
#pragma unroll
    for (int s = 2; s <= 13; ++s) {
        WAITB(4); STAGE(2 * s + 4); STAGE(2 * s + 5); COMPUTE(s);
    }
    // step14: Q=[S28,S29,st12,S30,S31,st13] -> wait(4)
    WAITB(4); COMPUTE(14);
    // step15: Q=[st12,S30,S31,st13,st14] -> wait(2) retires through S31
    WAITB(2); COMPUTE(15);

#undef STAGE
#undef COMPUTE
#undef WAITB
}

// ---------------------------------------------------------------------------
// K_s: per (b,l) block, iter-0 only (uniform c). s[v] = (1/64) sum_p u[p,v],
// fused squash. Thread t owns (pl = t>>4, v0 = (t&15)*4); ushort4 loads.
// ---------------------------------------------------------------------------
__global__ __launch_bounds__(256) void k_s(const ushort* __restrict__ uhat,
                                           float* __restrict__ vout) {
    const int l = blockIdx.x, b = blockIdx.y;
    const int t = threadIdx.x;
    const int w = t >> 6, lane = t & 63;
    const int pl = t >> 4;      // 0..15
    const int vg = t & 15;      // v0 = vg*4

    __shared__ float4 sl[4][16];

    const ushort* up = uhat + ((size_t)(b * L + l)) * P * V + (size_t)pl * V + vg * 4;

    float4 acc = {0.f, 0.f, 0.f, 0.f};
#pragma unroll 8
    for (int i = 0; i < 64; ++i) {
        ushort4 u = *reinterpret_cast<const ushort4*>(up + (size_t)i * 16 * V);
        acc.x += bf2f(u.x); acc.y += bf2f(u.y);
        acc.z += bf2f(u.z); acc.w += bf2f(u.w);
    }
    acc.x *= (1.f / 64.f); acc.y *= (1.f / 64.f);
    acc.z *= (1.f / 64.f); acc.w *= (1.f / 64.f);
#pragma unroll
    for (int m = 16; m <= 32; m <<= 1) {
        acc.x += __shfl_xor(acc.x, m, 64);
        acc.y += __shfl_xor(acc.y, m, 64);
        acc.z += __shfl_xor(acc.z, m, 64);
        acc.w += __shfl_xor(acc.w, m, 64);
    }
    if (lane < 16) sl[w][vg] = acc;
    __syncthreads();
    if (w == 0 && lane < 16) {
        float4 s0 = sl[0][vg], s1 = sl[1][vg], s2 = sl[2][vg], s3 = sl[3][vg];
        float4 s;
        s.x = s0.x + s1.x + s2.x + s3.x;
        s.y = s0.y + s1.y + s2.y + s3.y;
        s.z = s0.z + s1.z + s2.z + s3.z;
        s.w = s0.w + s1.w + s2.w + s3.w;
        float sq = s.x * s.x + s.y * s.y + s.z * s.z + s.w * s.w;
        sq += __shfl_xor(sq, 1, 64);
        sq += __shfl_xor(sq, 2, 64);
        sq += __shfl_xor(sq, 4, 64);
        sq += __shfl_xor(sq, 8, 64);
        float f = sqrtf(sq) / (1.0f + sq);
        float4 o = {s.x * f, s.y * f, s.z * f, s.w * f};
        *reinterpret_cast<float4*>(vout + (size_t)(b * L + l) * V + vg * 4) = o;
    }
}

// ---------------------------------------------------------------------------
// K_bc v6: block = (ch of 16 p, b), 512 threads (8 waves). u tile kept in
// REGISTERS (ur[8][2] ushort8/thread); LDS only vsh+bl (20 KB) -> 2 blocks/CU.
// phase 1: all 16 coalesced 1KB u-loads issued early, dot with v -> bl[p][l].
// phase 2: softmax over l per p (each wave 2 p's); b-logit update; optional T.
// phase 3: s-partial from registers, butterfly over pl8 -> sp[b][ch][l][v].
// ---------------------------------------------------------------------------
__global__ __launch_bounds__(512, 4) void k_bc(const ushort* __restrict__ uhat,
                                               const float* __restrict__ vv,
                                               float* __restrict__ bbuf,
                                               float* __restrict__ sp,
                                               float* __restrict__ Tsum,
                                               int add_prev, int do_T) {
    const int ch = blockIdx.x, b = blockIdx.y;
    const int p0 = ch * CHBC;
    const int t = threadIdx.x;
    const int w = t >> 6, lane = t & 63;
    const int pl8 = lane >> 3;   // p-local
    const int vg8 = lane & 7;    // v-octet
    const int l0 = w * 8;

    __shared__ float vsh[L][V];         // 16 KB
    __shared__ float bl[CHBC][L + 1];   // logits, then c in place
    __shared__ float twv[8];

    {
        const float4* vvp = reinterpret_cast<const float4*>(vv + (size_t)b * L * V);
        float4* vshp = reinterpret_cast<float4*>(&vsh[0][0]);
#pragma unroll
        for (int i = 0; i < 2; ++i) vshp[t + i * 512] = vvp[t + i * 512];
    }

    ushort8_t ur[8][2];
    {
        const ushort* ubase = uhat + (((size_t)(b * L + l0)) * P + p0 + pl8) * V + vg8 * 8;
#pragma unroll
        for (int li = 0; li < 8; ++li) {
#pragma unroll
            for (int ph = 0; ph < 2; ++ph)
                ur[li][ph] = *reinterpret_cast<const ushort8_t*>(
                    ubase + ((size_t)li * P + ph * 8) * V);
        }
    }
    __syncthreads();

#pragma unroll
    for (int li = 0; li < 8; ++li) {
        const int l = l0 + li;
        const float4 va = *reinterpret_cast<const float4*>(&vsh[l][vg8 * 8]);
        const float4 vb = *reinterpret_cast<const float4*>(&vsh[l][vg8 * 8 + 4]);
#pragma unroll
        for (int ph = 0; ph < 2; ++ph) {
            float d;
            d = bf2f(ur[li][ph][0]) * va.x;
            d = fmaf(bf2f(ur[li][ph][1]), va.y, d);
            d = fmaf(bf2f(ur[li][ph][2]), va.z, d);
            d = fmaf(bf2f(ur[li][ph][3]), va.w, d);
            d = fmaf(bf2f(ur[li][ph][4]), vb.x, d);
            d = fmaf(bf2f(ur[li][ph][5]), vb.y, d);
            d = fmaf(bf2f(ur[li][ph][6]), vb.z, d);
            d = fmaf(bf2f(ur[li][ph][7]), vb.w, d);
            d += __shfl_xor(d, 1, 64);
            d += __shfl_xor(d, 2, 64);
            d += __shfl_xor(d, 4, 64);
            if (vg8 == 0) bl[ph * 8 + pl8][l] = d;
        }
    }
    __syncthreads();

    float tloc = 0.f;
#pragma unroll
    for (int pi = 0; pi < 2; ++pi) {
        const int pli = w * 2 + pi;
        const int p = p0 + pli;
        float bv = bl[pli][lane];
        float* bp = bbuf + ((size_t)b * P + p) * L;
        if (add_prev) bv += bp[lane];
        bp[lane] = bv;
        float m = wmax64(bv);
        float e = __expf(bv - m);
        float ssum = wsum64(e);
        float cc = e / ssum;
        bl[pli][lane] = cc;
        if (do_T) tloc += cc * __logf(64.0f * (cc + 1e-12f));
    }
    if (do_T) {
        float dsum = wsum64(tloc);
        if (lane == 0) twv[w] = dsum;
    }
    __syncthreads();
    if (do_T && t == 0) {
        float s8 = twv[0] + twv[1] + twv[2] + twv[3] +
                   twv[4] + twv[5] + twv[6] + twv[7];
        atomicAdd(Tsum, s8 * (1.0f / LN64));
    }

    float* spb = sp + (size_t)(b * NCH_BC + ch) * L * V;
#pragma unroll
    for (int li = 0; li < 8; ++li) {
        const int l = l0 + li;
        const float cA = bl[pl8][l];
        const float cB = bl[8 + pl8][l];
        float4 pa, pb;
        pa.x = cA * bf2f(ur[li][0][0]) + cB * bf2f(ur[li][1][0]);
        pa.y = cA * bf2f(ur[li][0][1]) + cB * bf2f(ur[li][1][1]);
        pa.z = cA * bf2f(ur[li][0][2]) + cB * bf2f(ur[li][1][2]);
        pa.w = cA * bf2f(ur[li][0][3]) + cB * bf2f(ur[li][1][3]);
        pb.x = cA * bf2f(ur[li][0][4]) + cB * bf2f(ur[li][1][4]);
        pb.y = cA * bf2f(ur[li][0][5]) + cB * bf2f(ur[li][1][5]);
        pb.z = cA * bf2f(ur[li][0][6]) + cB * bf2f(ur[li][1][6]);
        pb.w = cA * bf2f(ur[li][0][7]) + cB * bf2f(ur[li][1][7]);
#pragma unroll
        for (int m = 8; m <= 32; m <<= 1) {
            pa.x += __shfl_xor(pa.x, m, 64);
            pa.y += __shfl_xor(pa.y, m, 64);
            pa.z += __shfl_xor(pa.z, m, 64);
            pa.w += __shfl_xor(pa.w, m, 64);
            pb.x += __shfl_xor(pb.x, m, 64);
            pb.y += __shfl_xor(pb.y, m, 64);
            pb.z += __shfl_xor(pb.z, m, 64);
            pb.w += __shfl_xor(pb.w, m, 64);
        }
        if (pl8 == 0) {
            *reinterpret_cast<float4*>(spb + (size_t)l * V + vg8 * 8) = pa;
            *reinterpret_cast<float4*>(spb + (size_t)l * V + vg8 * 8 + 4) = pb;
        }
    }
}

// ---------------------------------------------------------------------------
// K_v: chunk-reduce + squash. sp[b][ch][l][v]. grid (L/4, B); wave w -> l.
// ---------------------------------------------------------------------------
__global__ __launch_bounds__(256) void k_v(const float* __restrict__ sp,
                                           float* __restrict__ vout,
                                           float* __restrict__ norms) {
    const int b = blockIdx.y;
    const int w = threadIdx.x >> 6, lane = threadIdx.x & 63;
    const int l = blockIdx.x * 4 + w;
    const float* p = sp + ((size_t)b * NCH_BC * L + l) * V + lane;
    float s = 0.f;
#pragma unroll 8
    for (int ch = 0; ch < NCH_BC; ++ch) s += p[(size_t)ch * L * V];
    float sq = wsum64(s * s);
    float f = sqrtf(sq) / (1.0f + sq);
    vout[((size_t)b * L + l) * V + lane] = s * f;
    if (norms && lane == 0) norms[b * L + l] = sq / (1.0f + sq);
}

// ---------------------------------------------------------------------------
// K_final: T and D. One block, 64 threads (lane = l).
// ---------------------------------------------------------------------------
__global__ void k_final(const float* __restrict__ Tsum,
                        const float* __restrict__ norms,
                        float* __restrict__ out) {
    const int lane = threadIdx.x & 63;
    float n[B];
    float sum = 0.f;
#pragma unroll
    for (int b = 0; b < B; ++b) { n[b] = norms[b * L + lane]; sum += n[b]; }
    const float mean = sum * (1.0f / B);
    float var = 0.f;
#pragma unroll
    for (int b = 0; b < B; ++b) { float d = n[b] - mean; var = fmaf(d, d, var); }
    var *= (1.0f / B);
    float sd = sqrtf(var);
    float D = wmax64(sd);
    if (lane == 0) {
        out[B * L * V] = Tsum[0] * (1.0f / (B * P));
        out[B * L * V + 1] = D;
    }
}

extern "C" void kernel_launch(void* const* d_in, const int* in_sizes, int n_in,
                              void* d_out, int out_size, void* d_ws, size_t ws_size,
                              hipStream_t stream) {
    const float* x = (const float*)d_in[0];   // (B,P,Q)
    const float* W = (const float*)d_in[1];   // (L,P,V,Q)
    float* out = (float*)d_out;               // v (B,L,V) then T, D

    char* ws = (char*)d_ws;
    ushort* uhat = (ushort*)ws;                        // [b][l][p][v] bf16 = 128 MB
    size_t off = (size_t)B * L * P * V * 2;
    float* spbuf = (float*)(ws + off); off += (size_t)B * NCH_BC * L * V * 4;  // 16 MB
    float* vbuf  = (float*)(ws + off); off += (size_t)B * L * V * 4;
    float* bbuf  = (float*)(ws + off); off += (size_t)B * P * L * 4;           // 4 MB [b][p][l]
    float* norms = (float*)(ws + off); off += (size_t)B * L * 4;
    float* Tsum  = (float*)(ws + off); off += 256;

    hipMemsetAsync(Tsum, 0, sizeof(float), stream);

    // u_hat (wide 16B/lane stores, coalesced staged W reads)
    hipLaunchKernelGGL(k_uhat, dim3(2048), dim3(256), 0, stream, W, x, uhat);
    // iter 0: uniform c -> v0
    hipLaunchKernelGGL(k_s, dim3(L, B), dim3(256), 0, stream, uhat, vbuf);
    // b1 = v0.u ; c1 ; partial s1 (fused, u in registers)
    hipLaunchKernelGGL(k_bc, dim3(NCH_BC, B), dim3(512), 0, stream,
                       uhat, vbuf, bbuf, spbuf, Tsum, 0, 0);
    // v1
    hipLaunchKernelGGL(k_v, dim3(L / 4, B), dim3(256), 0, stream,
                       spbuf, vbuf, (float*)nullptr);
    // b2 = b1 + v1.u ; c2 ; T partials ; partial s2
    hipLaunchKernelGGL(k_bc, dim3(NCH_BC, B), dim3(512), 0, stream,
                       uhat, vbuf, bbuf, spbuf, Tsum, 1, 1);
    // v2 -> out, norms
    hipLaunchKernelGGL(k_v, dim3(L / 4, B), dim3(256), 0, stream,
                       spbuf, out, norms);
    hipLaunchKernelGGL(k_final, dim3(1), dim3(64), 0, stream, Tsum, norms, out);
}